// Round 4
// baseline (2677.358 us; speedup 1.0000x reference)
//
#include <hip/hip_runtime.h>
#include <stdint.h>

// Problem constants (B=4, S=2048, D=4096)
#define DDIM 4096
#define MTOK 8192
#define NT32 (DDIM / 32)     // 128 K-tiles of BK=32

typedef __attribute__((ext_vector_type(4))) int i32x4;
typedef __attribute__((ext_vector_type(16))) int i32x16;

__device__ __forceinline__ void async16(const void* g, void* l) {
    __builtin_amdgcn_global_load_lds(
        (const __attribute__((address_space(1))) unsigned int*)g,
        (__attribute__((address_space(3))) unsigned int*)l,
        16, 0, 0);
}

// ---------------- Fused quantization kernel (unchanged, ~35 us, HBM-bound) ----
__global__ __launch_bounds__(256) void quant_all(
    const float* __restrict__ x, const float* __restrict__ weight,
    const float* __restrict__ scales,
    signed char* __restrict__ qx, float* __restrict__ sx,
    signed char* __restrict__ qw, float* __restrict__ sw,
    const float* __restrict__ bias, float* __restrict__ bq)
{
    __shared__ float red[4];
    const int tid = threadIdx.x;
    const bool is_x = blockIdx.x < MTOK;
    const int row = is_x ? blockIdx.x : (blockIdx.x - MTOK);
    const float* src = is_x ? (x + (size_t)row * DDIM) : (weight + (size_t)row * DDIM);
    signed char* q = is_x ? qx : qw;
    float* srow = is_x ? sx : sw;

    const float4* s4 = (const float4*)scales;
    const float4* x4 = (const float4*)src;

    float4 v[4];
    float am = 0.0f;
#pragma unroll
    for (int j = 0; j < 4; ++j) {
        float4 a = x4[tid + j * 256];
        float4 s = s4[tid + j * 256];
        float4 r;
        if (is_x) { r.x = a.x * s.x; r.y = a.y * s.y; r.z = a.z * s.z; r.w = a.w * s.w; }
        else      { r.x = a.x / s.x; r.y = a.y / s.y; r.z = a.z / s.z; r.w = a.w / s.w; }
        v[j] = r;
        am = fmaxf(am, fmaxf(fmaxf(fabsf(r.x), fabsf(r.y)),
                             fmaxf(fabsf(r.z), fabsf(r.w))));
    }
#pragma unroll
    for (int off = 32; off > 0; off >>= 1)
        am = fmaxf(am, __shfl_xor(am, off, 64));
    if ((tid & 63) == 0) red[tid >> 6] = am;
    __syncthreads();
    am = fmaxf(fmaxf(red[0], red[1]), fmaxf(red[2], red[3]));
    am = fmaxf(am, 1e-8f);

    const float sc = 127.0f / am;
    uint32_t* qrow = (uint32_t*)(q + (size_t)row * DDIM);
#pragma unroll
    for (int j = 0; j < 4; ++j) {
        int q0 = (int)fminf(127.0f, fmaxf(-127.0f, rintf(v[j].x * sc)));
        int q1 = (int)fminf(127.0f, fmaxf(-127.0f, rintf(v[j].y * sc)));
        int q2 = (int)fminf(127.0f, fmaxf(-127.0f, rintf(v[j].z * sc)));
        int q3 = (int)fminf(127.0f, fmaxf(-127.0f, rintf(v[j].w * sc)));
        qrow[tid + j * 256] = (uint32_t)(q0 & 0xff) | ((uint32_t)(q1 & 0xff) << 8) |
                              ((uint32_t)(q2 & 0xff) << 16) | ((uint32_t)(q3 & 0xff) << 24);
    }
    if (tid == 0) {
        srow[row] = am * (1.0f / 127.0f);
        if (!is_x) bq[row] = bias[row] / scales[row];
    }
}

// ------- int8 GEMM: 256x256 tile, BK=32 ring-4, 64 KiB LDS, 2 blocks/CU -------
// out[m,n] = (sum_k qx[m,k]*qw[n,k]) * sx[m]*sw[n] + bq[n]
//
// R4 thesis: R1-R3 (1 block/CU, 128 KiB LDS) left all 4 SIMDs idle whenever
// the single resident block sat in its per-tile vmcnt/barrier/read window --
// MfmaUtil stuck at 33-40%. Fix = co-residency (m114 cross-block overlap):
// BK=32 ring-4 needs only 64 KiB -> 2 blocks/CU, grid = 512 = fully resident.
// Counted vmcnt kept (never 0 in main loop; depth-3 ring, 2 loads/tile).
//
// LDS geometry (the BK=32 bonus): [256 rows][32 B] per matrix per slot.
// A 32-row fragment = a CONTIGUOUS 1 KB block; lane addr = base + r5*32 + hi*16
// covers 64 distinct 16-B slots, each bank exactly 8 words -> ZERO bank
// conflicts, NO swizzle. Staging = 1 linear async16 per matrix per thread
// (row = tid>>1, 32 B contiguous per row via lane pairs; adjacent K-tiles
// cover adjacent 32 B of the same cache line within the ring window).
//
// Per tile: vmcnt(4); s_barrier; 6 ds_read_b128 (a0,b0,b1 | a1,a2,a3);
// STAGE(h+3); graded lgkmcnt(3/2/1/0) each releasing one MFMA pair
// (rule-18 sched_barrier(0) after every asm wait). setprio(1) around MFMAs
// (T5: phase diversity now supplied by the sibling block).
__global__ __launch_bounds__(512, 4) void gemm_i8(
    const signed char* __restrict__ qx, const signed char* __restrict__ qw,
    const float* __restrict__ sx, const float* __restrict__ sw,
    const float* __restrict__ bq, float* __restrict__ out)
{
    __shared__ __align__(16) signed char sA[4][256 * 32];
    __shared__ __align__(16) signed char sB[4][256 * 32];

    const int K = DDIM, N = DDIM;
    const int tid  = threadIdx.x;
    const int bm   = blockIdx.y;
    const int bn   = blockIdx.x;
    const int wave = tid >> 6;
    const int lane = tid & 63;
    const int wm   = (wave >> 2) << 7;  // 0 or 128
    const int wn   = (wave & 3) << 6;   // 0,64,128,192
    const int r5   = lane & 31;
    const int hi   = lane >> 5;

    const signed char* Ab = qx + (size_t)bm * 256 * K;
    const signed char* Bb = qw + (size_t)bn * 256 * K;

    // Staging: thread writes LDS bytes [tid*16, tid*16+16) = row tid>>1,
    // chunk tid&1; fetches the SAME (row, chunk) from global -- linear, no swizzle.
    const int g_row = tid >> 1;
    const int g_off = (tid & 1) * 16;
    const int dst0  = tid * 16;

    // Fragment lane offset within a contiguous 1 KB [32 x 32B] subtile:
    // lane l -> row r5, k-bytes hi*16..hi*16+15.
    const int loff = r5 * 32 + hi * 16;
    const int rA0 = (wm +  0) * 32 + loff;   // frag mi: rows wm+32*mi
    const int rA1 = (wm + 32) * 32 + loff;
    const int rA2 = (wm + 64) * 32 + loff;
    const int rA3 = (wm + 96) * 32 + loff;
    const int rB0 = (wn +  0) * 32 + loff;
    const int rB1 = (wn + 32) * 32 + loff;

    i32x16 acc[4][2] = {};

#define STAGE(t) do {                                                         \
        const int _s = (t) & 3;                                               \
        const size_t _k = (size_t)(t) * 32 + g_off;                           \
        async16(Ab + (size_t)g_row * K + _k, &sA[_s][dst0]);                  \
        async16(Bb + (size_t)g_row * K + _k, &sB[_s][dst0]);                  \
    } while (0)

    // Prologue: stage tiles 0,1,2 (6 loads in flight).
    STAGE(0);
    STAGE(1);
    STAGE(2);

    for (int h = 0; h < NT32; ++h) {
        // Counted wait: tile h's 2 loads are the oldest; <=4 outstanding
        // (tiles h+1,h+2) implies h retired. Never 0 until the last 2 tiles.
        if (h <= NT32 - 3)      asm volatile("s_waitcnt vmcnt(4)" ::: "memory");
        else if (h == NT32 - 2) asm volatile("s_waitcnt vmcnt(2)" ::: "memory");
        else                    asm volatile("s_waitcnt vmcnt(0)" ::: "memory");
        __builtin_amdgcn_s_barrier();
        __builtin_amdgcn_sched_barrier(0);

        const signed char* a = sA[h & 3];
        const signed char* b = sB[h & 3];

        // Read group 1 (a0,b0,b1) then group 2 (a1,a2,a3); order pinned so
        // graded lgkmcnt counts are exact (DS returns retire in order).
        i32x4 a0 = *(const i32x4*)&a[rA0];
        i32x4 b0 = *(const i32x4*)&b[rB0];
        i32x4 b1 = *(const i32x4*)&b[rB1];
        __builtin_amdgcn_sched_barrier(0);
        i32x4 a1 = *(const i32x4*)&a[rA1];
        i32x4 a2 = *(const i32x4*)&a[rA2];
        i32x4 a3 = *(const i32x4*)&a[rA3];
        __builtin_amdgcn_sched_barrier(0);

        // Prefetch tile h+3 into ring slot (h+3)&3 = slot h-1 (WAR-safe: all
        // waves finished slot h-1 reads -- lgkmcnt(0) before its last MFMAs --
        // before crossing barrier h above).
        if (h + 3 < NT32) STAGE(h + 3);
        __builtin_amdgcn_sched_barrier(0);

        __builtin_amdgcn_s_setprio(1);
        asm volatile("s_waitcnt lgkmcnt(3)" ::: "memory");  // a0,b0,b1 landed
        __builtin_amdgcn_sched_barrier(0);
        acc[0][0] = __builtin_amdgcn_mfma_i32_32x32x32_i8(a0, b0, acc[0][0], 0, 0, 0);
        acc[0][1] = __builtin_amdgcn_mfma_i32_32x32x32_i8(a0, b1, acc[0][1], 0, 0, 0);
        asm volatile("s_waitcnt lgkmcnt(2)" ::: "memory");  // a1 landed
        __builtin_amdgcn_sched_barrier(0);
        acc[1][0] = __builtin_amdgcn_mfma_i32_32x32x32_i8(a1, b0, acc[1][0], 0, 0, 0);
        acc[1][1] = __builtin_amdgcn_mfma_i32_32x32x32_i8(a1, b1, acc[1][1], 0, 0, 0);
        asm volatile("s_waitcnt lgkmcnt(1)" ::: "memory");  // a2 landed
        __builtin_amdgcn_sched_barrier(0);
        acc[2][0] = __builtin_amdgcn_mfma_i32_32x32x32_i8(a2, b0, acc[2][0], 0, 0, 0);
        acc[2][1] = __builtin_amdgcn_mfma_i32_32x32x32_i8(a2, b1, acc[2][1], 0, 0, 0);
        asm volatile("s_waitcnt lgkmcnt(0)" ::: "memory");  // a3 landed
        __builtin_amdgcn_sched_barrier(0);
        acc[3][0] = __builtin_amdgcn_mfma_i32_32x32x32_i8(a3, b0, acc[3][0], 0, 0, 0);
        acc[3][1] = __builtin_amdgcn_mfma_i32_32x32x32_i8(a3, b1, acc[3][1], 0, 0, 0);
        __builtin_amdgcn_s_setprio(0);
    }
#undef STAGE

    // Epilogue: 32x32 C/D layout col(n) = lane&31, row(m) = (reg&3)+8*(reg>>2)+4*hi
#pragma unroll
    for (int mi = 0; mi < 4; ++mi) {
        const int mbase = bm * 256 + wm + mi * 32 + 4 * hi;
        float sxv[16];
#pragma unroll
        for (int r = 0; r < 16; ++r)
            sxv[r] = sx[mbase + (r & 3) + 8 * (r >> 2)];
#pragma unroll
        for (int nj = 0; nj < 2; ++nj) {
            const int n = bn * 256 + wn + nj * 32 + r5;
            const float swn = sw[n];
            const float bqn = bq[n];
#pragma unroll
            for (int r = 0; r < 16; ++r) {
                const int m = mbase + (r & 3) + 8 * (r >> 2);
                out[(size_t)m * N + n] = (float)acc[mi][nj][r] * sxv[r] * swn + bqn;
            }
        }
    }
}

extern "C" void kernel_launch(void* const* d_in, const int* in_sizes, int n_in,
                              void* d_out, int out_size, void* d_ws, size_t ws_size,
                              hipStream_t stream) {
    const float* x      = (const float*)d_in[0];  // [4,2048,4096]
    const float* weight = (const float*)d_in[1];  // [4096,4096]
    const float* bias   = (const float*)d_in[2];  // [4096]
    const float* scales = (const float*)d_in[3];  // [4096]
    float* out = (float*)d_out;                   // [4,2048,4096]

    char* ws = (char*)d_ws;
    signed char* qx = (signed char*)ws;                       // 8192*4096 = 33554432 B
    signed char* qw = (signed char*)(ws + 33554432);          // 4096*4096 = 16777216 B
    float* sx = (float*)(ws + 50331648);                      // 8192*4 B
    float* sw = (float*)(ws + 50364416);                      // 4096*4 B
    float* bq = (float*)(ws + 50380800);                      // 4096*4 B

    quant_all<<<MTOK + DDIM, 256, 0, stream>>>(x, weight, scales, qx, sx, qw, sw, bias, bq);

    dim3 grid(DDIM / 256, MTOK / 256);  // (16, 32) = 512 blocks, ALL co-resident
    gemm_i8<<<grid, 512, 0, stream>>>(qx, qw, sx, sw, bq, out);
}